// Round 1
// baseline (647.196 us; speedup 1.0000x reference)
//
#include <hip/hip_runtime.h>
#include <hip/hip_bf16.h>

// Problem constants (from reference): B=8, T=4096, D=1024, fp32 in/out.
#define B_  8
#define T_  4096
#define D_  1024
#define M_  (B_*T_)          // 32768 rows for all GEMMs

// GEMM tile (m97 structure: 128x128 tile, BK=32, 4 waves, 16x16x32 bf16 MFMA)
#define BM 128
#define BN 128
#define BK 32

// Chunked scan
#define TC      64
#define NCHUNK  (T_/TC)      // 64

typedef short bf16x8 __attribute__((ext_vector_type(8)));
typedef float f32x4  __attribute__((ext_vector_type(4)));

__device__ __forceinline__ unsigned short f2bfu(float f) {
  __hip_bfloat16 b = __float2bfloat16(f);
  unsigned short s; __builtin_memcpy(&s, &b, 2); return s;
}
__device__ __forceinline__ float bfu2f(unsigned short v) {
  unsigned int t = ((unsigned int)v) << 16;
  float f; __builtin_memcpy(&f, &t, 4); return f;
}

// ---------------------------------------------------------------- cast fp32->bf16
__global__ __launch_bounds__(256) void cast_f32_bf16(const float* __restrict__ in,
                                                     unsigned short* __restrict__ out,
                                                     long long n) {
  size_t i = ((size_t)blockIdx.x * 256 + threadIdx.x) * 4;
  if (i >= (size_t)n) return;
  float4 v = *reinterpret_cast<const float4*>(in + i);
  ushort4 o = make_ushort4(f2bfu(v.x), f2bfu(v.y), f2bfu(v.z), f2bfu(v.w));
  *reinterpret_cast<ushort4*>(out + i) = o;
}

// ---------------------------------------------------------------- GEMM (A[M,K] x Bt[N,K]^T)
// EPI: 0 = fp32 out (+bias), 1 = bf16 out (+bias), 2 = bf16 sigmoid(out+bias)
template<int EPI>
__global__ __launch_bounds__(256) void gemm_bt(
    const __hip_bfloat16* __restrict__ A,
    const __hip_bfloat16* __restrict__ Bt,
    const float* __restrict__ bias,
    void* __restrict__ Cout, int M, int N, int K)
{
  __shared__ __align__(16) __hip_bfloat16 As[BM*BK];
  __shared__ __align__(16) __hip_bfloat16 Bs[BN*BK];

  const int tid = threadIdx.x;
  const int w   = tid >> 6;          // wave 0..3
  const int l   = tid & 63;
  const int wr  = (w >> 1) * 64;     // wave row offset in tile
  const int wc  = (w & 1)  * 64;     // wave col offset in tile
  const int lr  = l & 15;            // fragment row/col within 16
  const int lk  = (l >> 4) * 8;      // k-slice for A/B fragments

  const int brow = blockIdx.x * BM;
  const int bcol = blockIdx.y * BN;

  // staging: each thread issues 4 global_load_lds (2 for A, 2 for B), 16B each.
  // wave w fills rows [w*32, w*32+32) of the 128x32 tile; LDS dest is
  // wave-uniform base + lane*16 (hardware rule), layout is linear [128][32].
  const int srow = w*32 + (l >> 2);
  const int sk   = (l & 3) * 8;

  const __hip_bfloat16* Ag = A  + (size_t)(brow + srow)*K + sk;
  const __hip_bfloat16* Bg = Bt + (size_t)(bcol + srow)*K + sk;

  char* AsB = (char*)As + w*2048;
  char* BsB = (char*)Bs + w*2048;

  f32x4 acc[4][4] = {};

  for (int k0 = 0; k0 < K; k0 += BK) {
    __syncthreads();
#pragma unroll
    for (int j = 0; j < 2; ++j) {
      __builtin_amdgcn_global_load_lds(
          (const __attribute__((address_space(1))) void*)(Ag + (size_t)j*16*K + k0),
          (__attribute__((address_space(3))) void*)(AsB + j*1024), 16, 0, 0);
      __builtin_amdgcn_global_load_lds(
          (const __attribute__((address_space(1))) void*)(Bg + (size_t)j*16*K + k0),
          (__attribute__((address_space(3))) void*)(BsB + j*1024), 16, 0, 0);
    }
    __syncthreads();

    bf16x8 af[4], bfr[4];
#pragma unroll
    for (int m = 0; m < 4; ++m)
      af[m] = *reinterpret_cast<const bf16x8*>(As + (wr + m*16 + lr)*BK + lk);
#pragma unroll
    for (int n = 0; n < 4; ++n)
      bfr[n] = *reinterpret_cast<const bf16x8*>(Bs + (wc + n*16 + lr)*BK + lk);
#pragma unroll
    for (int m = 0; m < 4; ++m)
#pragma unroll
      for (int n = 0; n < 4; ++n)
        acc[m][n] = __builtin_amdgcn_mfma_f32_16x16x32_bf16(af[m], bfr[n], acc[m][n], 0, 0, 0);
  }

  float bv[4];
#pragma unroll
  for (int n = 0; n < 4; ++n) bv[n] = bias[bcol + wc + n*16 + lr];

  // C/D layout (verified m89/m91): col = lane&15, row = (lane>>4)*4 + j
#pragma unroll
  for (int m = 0; m < 4; ++m) {
#pragma unroll
    for (int n = 0; n < 4; ++n) {
      const int col = bcol + wc + n*16 + lr;
#pragma unroll
      for (int j = 0; j < 4; ++j) {
        const int row = brow + wr + m*16 + (l >> 4)*4 + j;
        float v = acc[m][n][j] + bv[n];
        if (EPI == 2) v = 1.0f / (1.0f + __expf(-v));
        if (EPI == 0) ((float*)Cout)[(size_t)row*N + col] = v;
        else          ((unsigned short*)Cout)[(size_t)row*N + col] = f2bfu(v);
      }
    }
  }
}

// ---------------------------------------------------------------- chunked scan
// h_t = g_t*h_{t-1} + (1-g_t)*u_t.  Within chunk c (zero init):
//   h_t = h_loc_t + A_t * carry_c,  A_t = prod_{s<=t in chunk} g_s
__global__ __launch_bounds__(256) void scan_phase1(
    const __hip_bfloat16* __restrict__ g,
    const __hip_bfloat16* __restrict__ u,
    unsigned short* __restrict__ hloc,
    unsigned short* __restrict__ Aout,
    float* __restrict__ P, float* __restrict__ Hend)
{
  const int d = blockIdx.x * 256 + threadIdx.x;   // 0..D-1
  const int c = blockIdx.y;                        // chunk
  const int b = blockIdx.z;
  size_t idx = ((size_t)b*T_ + (size_t)c*TC) * D_ + d;
  float h = 0.0f, A = 1.0f;
#pragma unroll 4
  for (int t = 0; t < TC; ++t, idx += D_) {
    float gv = __bfloat162float(g[idx]);
    float uv = __bfloat162float(u[idx]);
    h = gv*h + (1.0f - gv)*uv;
    A *= gv;
    hloc[idx] = f2bfu(h);
    Aout[idx] = f2bfu(A);
  }
  const size_t ci = ((size_t)b*NCHUNK + c)*D_ + d;
  P[ci]    = A;
  Hend[ci] = h;
}

__global__ __launch_bounds__(256) void scan_phase2(
    const float* __restrict__ P, const float* __restrict__ Hend,
    float* __restrict__ carry)
{
  const int gid = blockIdx.x * 256 + threadIdx.x;  // over B*D
  const int b  = gid / D_;
  const int dd = gid % D_;
  float cy = 0.0f;
#pragma unroll 4
  for (int c = 0; c < NCHUNK; ++c) {
    const size_t ci = ((size_t)b*NCHUNK + c)*D_ + dd;
    carry[ci] = cy;                    // carry INTO chunk c
    cy = Hend[ci] + P[ci]*cy;
  }
}

__global__ __launch_bounds__(256) void scan_phase3(
    unsigned short* __restrict__ h,        // in: hloc, out: final h (in place)
    const unsigned short* __restrict__ Aout,
    const float* __restrict__ carry)
{
  const size_t i4  = (size_t)blockIdx.x * 256 + threadIdx.x;  // unit of 4 elems
  const int d4     = D_ / 4;
  const int dd4    = (int)(i4 % d4);
  const size_t bt  = i4 / d4;           // b*T + t
  const int t      = (int)(bt % T_);
  const int b      = (int)(bt / T_);
  const int c      = t / TC;
  const size_t idx = bt * D_ + (size_t)dd4 * 4;

  ushort4 hv = *reinterpret_cast<const ushort4*>(h + idx);
  ushort4 av = *reinterpret_cast<const ushort4*>(Aout + idx);
  float4  cv = *reinterpret_cast<const float4*>(carry + ((size_t)b*NCHUNK + c)*D_ + (size_t)dd4*4);

  ushort4 o;
  o.x = f2bfu(bfu2f(hv.x) + bfu2f(av.x)*cv.x);
  o.y = f2bfu(bfu2f(hv.y) + bfu2f(av.y)*cv.y);
  o.z = f2bfu(bfu2f(hv.z) + bfu2f(av.z)*cv.z);
  o.w = f2bfu(bfu2f(hv.w) + bfu2f(av.w)*cv.w);
  *reinterpret_cast<ushort4*>(h + idx) = o;
}

// ---------------------------------------------------------------- launch
extern "C" void kernel_launch(void* const* d_in, const int* in_sizes, int n_in,
                              void* d_out, int out_size, void* d_ws, size_t ws_size,
                              hipStream_t stream) {
  const float* x  = (const float*)d_in[0];
  const float* Wi = (const float*)d_in[1];
  const float* bi = (const float*)d_in[2];
  const float* Wg = (const float*)d_in[3];
  const float* bg = (const float*)d_in[4];
  const float* Wo = (const float*)d_in[5];
  const float* bo = (const float*)d_in[6];

  const size_t NX = (size_t)M_ * D_;    // 33,554,432
  const size_t NW = (size_t)D_ * D_;    // 1,048,576
  const size_t NC = (size_t)B_ * NCHUNK * D_;  // 524,288

  char* p = (char*)d_ws;
  __hip_bfloat16* xb  = (__hip_bfloat16*)p; p += NX*2;
  __hip_bfloat16* wib = (__hip_bfloat16*)p; p += NW*2;
  __hip_bfloat16* wgb = (__hip_bfloat16*)p; p += NW*2;
  __hip_bfloat16* wob = (__hip_bfloat16*)p; p += NW*2;
  unsigned short* ub  = (unsigned short*)p; p += NX*2;
  unsigned short* gb  = (unsigned short*)p; p += NX*2;
  unsigned short* hb  = (unsigned short*)p; p += NX*2;   // hloc, then final h in place
  unsigned short* Ab  = (unsigned short*)p; p += NX*2;
  float* P     = (float*)p; p += NC*4;
  float* Hend  = (float*)p; p += NC*4;
  float* carry = (float*)p; p += NC*4;

  // casts
  cast_f32_bf16<<<(int)(NX/4/256), 256, 0, stream>>>(x,  (unsigned short*)xb,  (long long)NX);
  cast_f32_bf16<<<(int)(NW/4/256), 256, 0, stream>>>(Wi, (unsigned short*)wib, (long long)NW);
  cast_f32_bf16<<<(int)(NW/4/256), 256, 0, stream>>>(Wg, (unsigned short*)wgb, (long long)NW);
  cast_f32_bf16<<<(int)(NW/4/256), 256, 0, stream>>>(Wo, (unsigned short*)wob, (long long)NW);

  dim3 gg(M_/BM, D_/BN);   // (256, 8)
  gemm_bt<1><<<gg, 256, 0, stream>>>(xb, wib, bi, (void*)ub, M_, D_, D_);
  gemm_bt<2><<<gg, 256, 0, stream>>>(xb, wgb, bg, (void*)gb, M_, D_, D_);

  scan_phase1<<<dim3(D_/256, NCHUNK, B_), 256, 0, stream>>>(
      (const __hip_bfloat16*)gb, (const __hip_bfloat16*)ub, hb, Ab, P, Hend);
  scan_phase2<<<(B_*D_)/256, 256, 0, stream>>>(P, Hend, carry);
  scan_phase3<<<(int)(NX/4/256), 256, 0, stream>>>(hb, Ab, carry);

  gemm_bt<0><<<gg, 256, 0, stream>>>((const __hip_bfloat16*)hb, wob, bo,
                                     d_out, M_, D_, D_);
}

// Round 2
// 533.124 us; speedup vs baseline: 1.2140x; 1.2140x over previous
//
#include <hip/hip_runtime.h>
#include <hip/hip_bf16.h>

// RG-LRU: B=8, T=4096, D=1024, fp32 in/out.
#define B_  8
#define T_  4096
#define D_  1024
#define M_  (B_*T_)          // 32768
#define NT  16               // K=1024 / BK=64 K-tiles
#define TC      64
#define NCHUNK  (T_/TC)      // 64

typedef short bf16x8 __attribute__((ext_vector_type(8)));
typedef float f32x4  __attribute__((ext_vector_type(4)));

__device__ __forceinline__ unsigned short f2bfu(float f) {
  __hip_bfloat16 b = __float2bfloat16(f);
  unsigned short s; __builtin_memcpy(&s, &b, 2); return s;
}
__device__ __forceinline__ float bfu2f(unsigned short v) {
  unsigned int t = ((unsigned int)v) << 16;
  float f; __builtin_memcpy(&f, &t, 4); return f;
}

// ---------------------------------------------------------------- cast fp32->bf16
__global__ __launch_bounds__(256) void cast_f32_bf16(const float* __restrict__ in,
                                                     unsigned short* __restrict__ out,
                                                     long long n) {
  size_t i = ((size_t)blockIdx.x * 256 + threadIdx.x) * 4;
  if (i >= (size_t)n) return;
  float4 v = *reinterpret_cast<const float4*>(in + i);
  ushort4 o = make_ushort4(f2bfu(v.x), f2bfu(v.y), f2bfu(v.z), f2bfu(v.w));
  *reinterpret_cast<ushort4*>(out + i) = o;
}

// ---------------------------------------------------------------- 256^2 4-phase GEMM
// C[M,N] = A[M,K] * Bt[N,K]^T (+bias). 512 thr = 8 waves (2M x 4N), BK=64,
// double-buffered LDS 128KB, K-slice half-tiles, counted vmcnt(4) gates,
// XOR slot swizzle phys = slot ^ ((row>>1)&3) on 64B rows (2-way = free).
// LDS map: [c][mat][kk][256 rows][32 cols bf16]; mat A at +0, B at +32768.
// EPI: 0 fp32 out, 1 bf16 out, 2 bf16 sigmoid out.

#define GLL(gsrc, loff) __builtin_amdgcn_global_load_lds( \
  (const __attribute__((address_space(1))) void*)(gsrc), \
  (__attribute__((address_space(3))) void*)(lds + (loff)), 16, 0, 0)

// stage one half (=16KB = one kk-slice of one matrix): 2 loads/wave
#define STAGE(basePtr, matOff, cbuf, kkh, k0g) do { \
  GLL((basePtr) + (size_t)(k0g) + (kkh)*32, \
      (cbuf)*65536 + (matOff) + (kkh)*16384 + (w*32)*64); \
  GLL((basePtr) + (size_t)(k0g) + (kkh)*32 + 16*1024, \
      (cbuf)*65536 + (matOff) + (kkh)*16384 + (w*32 + 16)*64); \
} while (0)

#define GATE4 asm volatile("s_waitcnt vmcnt(4)" ::: "memory")
#define NOGATE (void)0

// one phase: 4 A-frag reads (+4 B-frag reads on LOADB), stage 1 half,
// barrier, 16 MFMA (setprio-wrapped), optional gate, barrier.
#define PH(kk, mh, LOADB, STAGE_STMT, GATE_STMT) do { \
  _Pragma("unroll") \
  for (int q = 0; q < 4; ++q) \
    aF[q] = *reinterpret_cast<const bf16x8*>(lds + c*65536 + (kk)*16384 + ((mh)*4+q)*1024 + aoff); \
  if (LOADB) { \
    _Pragma("unroll") \
    for (int q = 0; q < 4; ++q) \
      bF[q] = *reinterpret_cast<const bf16x8*>(lds + c*65536 + 32768 + (kk)*16384 + q*1024 + boff); \
  } \
  STAGE_STMT; \
  __builtin_amdgcn_s_barrier(); \
  __builtin_amdgcn_s_setprio(1); \
  _Pragma("unroll") \
  for (int q = 0; q < 4; ++q) { \
    _Pragma("unroll") \
    for (int n = 0; n < 4; ++n) \
      acc[(mh)*4+q][n] = __builtin_amdgcn_mfma_f32_16x16x32_bf16(aF[q], bF[n], acc[(mh)*4+q][n], 0, 0, 0); \
  } \
  __builtin_amdgcn_s_setprio(0); \
  GATE_STMT; \
  __builtin_amdgcn_s_barrier(); \
} while (0)

template<int EPI>
__global__ __launch_bounds__(512, 2) void gemm256(
    const __hip_bfloat16* __restrict__ A,
    const __hip_bfloat16* __restrict__ Bt,
    const float* __restrict__ bias,
    void* __restrict__ Cout)
{
  __shared__ __align__(1024) char lds[131072];

  const int tid = threadIdx.x;
  const int w  = tid >> 6;          // wave 0..7
  const int l  = tid & 63;
  const int wm = w >> 2;            // 0..1 (M half)
  const int wn = w & 3;             // 0..3 (N quarter)
  const int lr = l & 15;
  const int hk = l >> 4;            // 0..3 k-slot

  const int brow = blockIdx.x * 256;
  const int bcol = blockIdx.y * 256;

  // staging per-lane constants: chunk = 16 rows x 64B; lane row l>>2, slot l&3.
  // source slot pre-swizzled so LDS[row][s] holds global (row, s ^ ((row>>1)&3)).
  const int srow  = l >> 2;
  const int sslot = (l & 3) ^ ((l >> 3) & 3);
  const __hip_bfloat16* Abase = A  + (size_t)(brow + w*32 + srow)*1024 + sslot*8;
  const __hip_bfloat16* Bbase = Bt + (size_t)(bcol + w*32 + srow)*1024 + sslot*8;

  // frag-read offsets: byte = row*64 + (hk ^ ((lr>>1)&3))*16 within a kk-half
  const int aoff = (wm*128 + lr)*64 + ((hk ^ ((lr >> 1) & 3)) * 16);
  const int boff = (wn*64  + lr)*64 + ((hk ^ ((lr >> 1) & 3)) * 16);

  f32x4 acc[8][4] = {};
  bf16x8 aF[4], bF[4];

  // prologue: stage tile 0 (A0,B0,A1,B1), gate on first two halves
  STAGE(Abase, 0,     0, 0, 0);
  STAGE(Bbase, 32768, 0, 0, 0);
  STAGE(Abase, 0,     0, 1, 0);
  STAGE(Bbase, 32768, 0, 1, 0);
  GATE4;
  __builtin_amdgcn_s_barrier();

  for (int t = 0; t < NT; ++t) {
    const int c  = t & 1;
    const int cn = c ^ 1;
    const int k0n = (t + 1 < NT ? t + 1 : 0) * 64;   // last-tile stage wraps (dummy)
    PH(0, 0, 1, STAGE(Abase, 0,     cn, 0, k0n), NOGATE);
    PH(0, 1, 0, STAGE(Bbase, 32768, cn, 0, k0n), GATE4);   // gates A1^t,B1^t for p2
    PH(1, 0, 1, STAGE(Abase, 0,     cn, 1, k0n), NOGATE);
    PH(1, 1, 0, STAGE(Bbase, 32768, cn, 1, k0n), GATE4);   // gates A0^{t+1},B0^{t+1}
  }
  asm volatile("s_waitcnt vmcnt(0)" ::: "memory");

  float bv[4];
#pragma unroll
  for (int n = 0; n < 4; ++n) bv[n] = bias[bcol + wn*64 + n*16 + lr];

  // C/D layout: col = lane&15, row = (lane>>4)*4 + j (verified round 1)
#pragma unroll
  for (int mi = 0; mi < 8; ++mi) {
#pragma unroll
    for (int n = 0; n < 4; ++n) {
      const int col = bcol + wn*64 + n*16 + lr;
#pragma unroll
      for (int j = 0; j < 4; ++j) {
        const int row = brow + wm*128 + mi*16 + hk*4 + j;
        float v = acc[mi][n][j] + bv[n];
        if (EPI == 2) v = 1.0f / (1.0f + __expf(-v));
        if (EPI == 0) ((float*)Cout)[(size_t)row*D_ + col] = v;
        else          ((unsigned short*)Cout)[(size_t)row*D_ + col] = f2bfu(v);
      }
    }
  }
}

// ---------------------------------------------------------------- chunked scan
// h_t = g_t*h_{t-1} + (1-g_t)*u_t.
// phase1: per-chunk summaries only (P = prod g, Hend = local scan end, h0=0).
// phase2: serial inter-chunk carry.
// phase3: RE-scan each chunk with h_init = carry (exact recurrence), write bf16 h.
__global__ __launch_bounds__(256) void scan_phase1(
    const unsigned short* __restrict__ g,
    const unsigned short* __restrict__ u,
    float* __restrict__ P, float* __restrict__ Hend)
{
  const int c = blockIdx.x, b = blockIdx.y;
  const int d0 = threadIdx.x * 4;
  size_t idx = (((size_t)b*T_ + (size_t)c*TC) * D_ + d0) / 4;  // ushort4 units
  const ushort4* g4 = reinterpret_cast<const ushort4*>(g);
  const ushort4* u4 = reinterpret_cast<const ushort4*>(u);
  float h[4] = {0,0,0,0}, A[4] = {1,1,1,1};
#pragma unroll 4
  for (int t = 0; t < TC; ++t, idx += D_/4) {
    ushort4 gv = g4[idx], uv = u4[idx];
    float gf[4] = {bfu2f(gv.x), bfu2f(gv.y), bfu2f(gv.z), bfu2f(gv.w)};
    float uf[4] = {bfu2f(uv.x), bfu2f(uv.y), bfu2f(uv.z), bfu2f(uv.w)};
#pragma unroll
    for (int k = 0; k < 4; ++k) { h[k] = gf[k]*h[k] + (1.0f - gf[k])*uf[k]; A[k] *= gf[k]; }
  }
  const size_t ci = ((size_t)b*NCHUNK + c)*D_ + d0;
  *reinterpret_cast<float4*>(P + ci)    = make_float4(A[0], A[1], A[2], A[3]);
  *reinterpret_cast<float4*>(Hend + ci) = make_float4(h[0], h[1], h[2], h[3]);
}

__global__ __launch_bounds__(256) void scan_phase2(
    const float* __restrict__ P, const float* __restrict__ Hend,
    float* __restrict__ carry)
{
  const int gid = blockIdx.x * 256 + threadIdx.x;  // over B*D
  const int b  = gid >> 10;
  const int dd = gid & (D_ - 1);
  float cy = 0.0f;
#pragma unroll 4
  for (int c = 0; c < NCHUNK; ++c) {
    const size_t ci = ((size_t)b*NCHUNK + c)*D_ + dd;
    carry[ci] = cy;                    // carry INTO chunk c
    cy = Hend[ci] + P[ci]*cy;
  }
}

__global__ __launch_bounds__(256) void scan_phase3(
    const unsigned short* __restrict__ g,
    const unsigned short* __restrict__ u,
    const float* __restrict__ carry,
    unsigned short* __restrict__ hout)
{
  const int c = blockIdx.x, b = blockIdx.y;
  const int d0 = threadIdx.x * 4;
  size_t idx = (((size_t)b*T_ + (size_t)c*TC) * D_ + d0) / 4;
  const ushort4* g4 = reinterpret_cast<const ushort4*>(g);
  const ushort4* u4 = reinterpret_cast<const ushort4*>(u);
  ushort4* h4 = reinterpret_cast<ushort4*>(hout);
  float4 cv = *reinterpret_cast<const float4*>(carry + ((size_t)b*NCHUNK + c)*D_ + d0);
  float h[4] = {cv.x, cv.y, cv.z, cv.w};
#pragma unroll 4
  for (int t = 0; t < TC; ++t, idx += D_/4) {
    ushort4 gv = g4[idx], uv = u4[idx];
#pragma unroll
    for (int k = 0; k < 4; ++k) {
      float gf = bfu2f(k==0?gv.x:k==1?gv.y:k==2?gv.z:gv.w);
      float uf = bfu2f(k==0?uv.x:k==1?uv.y:k==2?uv.z:uv.w);
      h[k] = gf*h[k] + (1.0f - gf)*uf;
    }
    h4[idx] = make_ushort4(f2bfu(h[0]), f2bfu(h[1]), f2bfu(h[2]), f2bfu(h[3]));
  }
}

// ---------------------------------------------------------------- launch
extern "C" void kernel_launch(void* const* d_in, const int* in_sizes, int n_in,
                              void* d_out, int out_size, void* d_ws, size_t ws_size,
                              hipStream_t stream) {
  const float* x  = (const float*)d_in[0];
  const float* Wi = (const float*)d_in[1];
  const float* bi = (const float*)d_in[2];
  const float* Wg = (const float*)d_in[3];
  const float* bg = (const float*)d_in[4];
  const float* Wo = (const float*)d_in[5];
  const float* bo = (const float*)d_in[6];

  const size_t NX = (size_t)M_ * D_;           // 33.5M
  const size_t NW = (size_t)D_ * D_;           // 1.05M
  const size_t NC = (size_t)B_ * NCHUNK * D_;  // 524K

  char* p = (char*)d_ws;
  __hip_bfloat16* xb  = (__hip_bfloat16*)p; p += NX*2;
  __hip_bfloat16* wib = (__hip_bfloat16*)p; p += NW*2;
  __hip_bfloat16* wgb = (__hip_bfloat16*)p; p += NW*2;
  __hip_bfloat16* wob = (__hip_bfloat16*)p; p += NW*2;
  unsigned short* ub  = (unsigned short*)p; p += NX*2;
  unsigned short* gb  = (unsigned short*)p; p += NX*2;
  unsigned short* hb  = (unsigned short*)p; p += NX*2;
  float* P     = (float*)p; p += NC*4;
  float* Hend  = (float*)p; p += NC*4;
  float* carry = (float*)p; p += NC*4;

  cast_f32_bf16<<<(int)(NX/4/256), 256, 0, stream>>>(x,  (unsigned short*)xb,  (long long)NX);
  cast_f32_bf16<<<(int)(NW/4/256), 256, 0, stream>>>(Wi, (unsigned short*)wib, (long long)NW);
  cast_f32_bf16<<<(int)(NW/4/256), 256, 0, stream>>>(Wg, (unsigned short*)wgb, (long long)NW);
  cast_f32_bf16<<<(int)(NW/4/256), 256, 0, stream>>>(Wo, (unsigned short*)wob, (long long)NW);

  dim3 gg(M_/256, D_/256);   // (128, 4)
  gemm256<1><<<gg, 512, 0, stream>>>(xb, wib, bi, (void*)ub);
  gemm256<2><<<gg, 512, 0, stream>>>(xb, wgb, bg, (void*)gb);

  scan_phase1<<<dim3(NCHUNK, B_), 256, 0, stream>>>(gb, ub, P, Hend);
  scan_phase2<<<(B_*D_)/256, 256, 0, stream>>>(P, Hend, carry);
  scan_phase3<<<dim3(NCHUNK, B_), 256, 0, stream>>>(gb, ub, carry, hb);

  gemm256<0><<<gg, 512, 0, stream>>>((const __hip_bfloat16*)hb, wob, bo, d_out);
}